// Round 1
// 185.186 us; speedup vs baseline: 1.0845x; 1.0845x over previous
//
#include <hip/hip_runtime.h>

#define DD 256
#define HH 512
#define BB 128
#define TS 4096   // floats per tape block (16 KB)

#define WAITVM(N) asm volatile("s_waitcnt vmcnt(" #N ")" ::: "memory")
#define SYNC() do { __builtin_amdgcn_s_barrier(); __builtin_amdgcn_sched_barrier(0); } while (0)

__device__ __forceinline__ float elu_f(float x) {
    return x > 0.f ? x : (__expf(x) - 1.f);
}
__device__ __forceinline__ float rlf(float v, int l) {
    return __uint_as_float(__builtin_amdgcn_readlane(__float_as_uint(v), (unsigned)l));
}
__device__ __forceinline__ float f4c(const float4& v, int r) {
    return r == 0 ? v.x : r == 1 ? v.y : r == 2 ? v.z : v.w;
}

// Unit slot map: lane L, A-reg r (0..3) <-> h = L+64r  [exception (63,3) -> h=510]
//                lane L, B-reg 4+r     <-> h = 255+L+64r [exception (63,3) -> h=511]
__device__ __forceinline__ int pmap(int h) {
    if (h == 510) return 255;
    if (h == 511) return 511;
    return (h < 255) ? (4 * (h & 63) + (h >> 6))
                     : (256 + 4 * ((h - 255) & 63) + ((h - 255) >> 6));
}
__device__ __forceinline__ int p4map(int j) {      // j in [0,256): column map
    return 4 * (j & 63) + (j >> 6);
}
__device__ __forceinline__ int w1base(int hp) {    // m at +0, l at +512
    return (hp <= 254) ? hp * TS
         : (hp <= 509) ? (hp - 255) * TS + 1024
         : 255 * TS + ((hp == 510) ? 0 : 1024);
}
__device__ __forceinline__ int wobase(int hp) {    // m at +0, l at +256
    return (hp <= 254) ? hp * TS + 3072
         : (hp <= 509) ? (hp - 255) * TS + 3584
         : 255 * TS + ((hp == 510) ? 2048 : 2560);
}

// Tape block i (4096 floats), rows lane-packed [pos = p(h) or p4(j)]:
//  [0/512]    W1T[i]     m/l     [1024/1536] W1T[i+255] m/l
//  [2048/2560] W0T[i]    m/l     [3072/3328] WoT[i]     m/l (256)
//  [3584/3840] WoT[i+255] m/l
// Block 255 = appendix: W1T[510] m/l @0/512, W1T[511] m/l @1024/1536,
//  WoT[510] m/l @2048/2304, WoT[511] m/l @2560/2816.  [3072..4095 unused]
__global__ __launch_bounds__(256) void prep(
    const float* __restrict__ w0m_, const float* __restrict__ w0l_,
    const float* __restrict__ w1m_, const float* __restrict__ w1l_,
    const float* __restrict__ wom_, const float* __restrict__ wol_,
    float* __restrict__ tape)
{
    __shared__ float tm[32][33], tl[32][33];
    const int tx = threadIdx.x & 31, ty = threadIdx.x >> 5;
    const unsigned b = blockIdx.x;

    if (b < 256) {                              // W1: 16 h-tiles x 16 hp-tiles
        const int h0 = (int)(b >> 4) << 5, hp0 = (int)(b & 15) << 5;
        #pragma unroll
        for (int j = 0; j < 4; ++j) {
            int r = ty + 8 * j;
            tm[r][tx] = w1m_[(h0 + r) * HH + hp0 + tx];
            tl[r][tx] = w1l_[(h0 + r) * HH + hp0 + tx];
        }
        __syncthreads();
        #pragma unroll
        for (int j = 0; j < 4; ++j) {
            int hp = hp0 + ty + 8 * j;
            int h  = h0 + tx;
            int dh_h = (h <= 254) ? h + 1 : (h <= 509 ? h - 254 : h - 509);
            int dh_p = (hp <= 254) ? hp + 1 : (hp <= 509 ? hp - 254 : hp - 509);
            float mask = (dh_h >= dh_p) ? 1.f : 0.f;
            int base = w1base(hp), p = pmap(h);
            tape[base + p]       = mask * tm[tx][ty + 8 * j];
            tape[base + 512 + p] = mask * tl[tx][ty + 8 * j];
        }
    } else if (b < 384) {                       // W0: 16 h-tiles x 8 i-tiles
        const int b2 = (int)b - 256;
        const int h0 = (b2 >> 3) << 5, i0 = (b2 & 7) << 5;
        #pragma unroll
        for (int j = 0; j < 4; ++j) {
            int r = ty + 8 * j;
            tm[r][tx] = w0m_[(h0 + r) * DD + i0 + tx];
            tl[r][tx] = w0l_[(h0 + r) * DD + i0 + tx];
        }
        __syncthreads();
        #pragma unroll
        for (int j = 0; j < 4; ++j) {
            int i = i0 + ty + 8 * j;
            int h = h0 + tx;
            int p = pmap(h);
            tape[i * TS + 2048 + p] = tm[tx][ty + 8 * j];
            tape[i * TS + 2560 + p] = tl[tx][ty + 8 * j];
        }
    } else {                                    // Wo: 8 j-tiles x 16 hp-tiles
        const int b3 = (int)b - 384;
        const int j0 = (b3 >> 4) << 5, hp0 = (b3 & 15) << 5;
        #pragma unroll
        for (int j = 0; j < 4; ++j) {
            int r = ty + 8 * j;
            tm[r][tx] = wom_[(j0 + r) * HH + hp0 + tx];
            tl[r][tx] = wol_[(j0 + r) * HH + hp0 + tx];
        }
        __syncthreads();
        #pragma unroll
        for (int j = 0; j < 4; ++j) {
            int hp = hp0 + ty + 8 * j;
            int jj = j0 + tx;
            int base = wobase(hp), p = p4map(jj);
            tape[base + p]       = tm[tx][ty + 8 * j];
            tape[base + 256 + p] = tl[tx][ty + 8 * j];
        }
    }
}

// ================================ main =====================================
struct WSet { float4 w[16]; };

// producer: stage one 16 KB group into an LDS ring slot via direct-to-LDS DMA.
// Layout is linear: chunk k, lane L -> lds[k*256 + 4L .. +3] (wave-uniform base
// + lane*16, exactly the HW pattern of global_load_lds width 16).
__device__ __forceinline__ void stage16(const float* g, float* l, int lane) {
    #pragma unroll
    for (int k = 0; k < 16; ++k) {
        __builtin_amdgcn_global_load_lds(
            (const __attribute__((address_space(1))) void*)(g + 256 * k + 4 * lane),
            (__attribute__((address_space(3))) void*)(l + 256 * k),
            16, 0, 0);
    }
}

// consumer: LDS ring slot -> register weight set (16x ds_read_b128,
// stride-16B contiguous per lane -> conflict-free).
__device__ __forceinline__ void rd_set(WSet& S, const float* b, int lane) {
    const float4* p = (const float4*)b;
    #pragma unroll
    for (int k = 0; k < 16; ++k) S.w[k] = p[64 * k + lane];
}

// w[0..3]=W1T[i] mA,mB,lA,lB  w[4..7]=W1T[i+255] mA,mB,lA,lB
// w[8..11]=W0T[i] mA,mB,lA,lB  w[12..15]=WoT[i]m, WoT[i]l, WoT[i+255]m, WoT[i+255]l
template<int Q, int EX>
__device__ __forceinline__ void stepC(
    int t, int lane, const WSet& S,
    float (&a0m)[8], float (&a0l)[8], float (&a1m)[8], float (&a1l)[8],
    float (&Rm)[4], float (&Rl)[4], float (&yv)[4],
    const float (&xv)[4], const float (&bmv)[4], const float (&blv)[4],
    float& ls_sum,
    const float4& exmA, const float4& exmB, const float4& exlA, const float4& exlB,
    const float4& exwm, const float4& exwl)
{
    float mu = rlf(Rm[Q], t) + rlf(bmv[Q], t);
    float ls = 0.5f * (rlf(Rl[Q], t) + rlf(blv[Q], t));
    ls_sum += ls;
    float v = __fdividef(rlf(xv[Q], t) - mu, __expf(ls) + 1e-12f);
    yv[Q] = (lane == t) ? v : yv[Q];

    #pragma unroll
    for (int r = Q; r < 4; ++r) {
        a0m[r]     += v * f4c(S.w[8], r);
        a0m[4 + r] += v * f4c(S.w[9], r);
        a0l[r]     += v * f4c(S.w[10], r);
        a0l[4 + r] += v * f4c(S.w[11], r);
    }

    float p0m = elu_f(rlf(a0m[Q], t)),     p0l = elu_f(rlf(a0l[Q], t));
    float p1m = elu_f(rlf(a0m[4 + Q], t)), p1l = elu_f(rlf(a0l[4 + Q], t));
    float p2m = 0.f, p2l = 0.f;
    if (EX) {
        p2m = elu_f(rlf(a0m[EX == 1 ? 3 : 7], 63));
        p2l = elu_f(rlf(a0l[EX == 1 ? 3 : 7], 63));
    }

    #pragma unroll
    for (int r = Q; r < 4; ++r) {
        a1m[r]     += f4c(S.w[0], r) * p0m + f4c(S.w[4], r) * p1m;
        a1m[4 + r] += f4c(S.w[1], r) * p0m + f4c(S.w[5], r) * p1m;
        a1l[r]     += f4c(S.w[2], r) * p0l + f4c(S.w[6], r) * p1l;
        a1l[4 + r] += f4c(S.w[3], r) * p0l + f4c(S.w[7], r) * p1l;
    }
    if (EX) {
        #pragma unroll
        for (int r = 0; r < 4; ++r) {
            a1m[r]     += f4c(exmA, r) * p2m;
            a1m[4 + r] += f4c(exmB, r) * p2m;
            a1l[r]     += f4c(exlA, r) * p2l;
            a1l[4 + r] += f4c(exlB, r) * p2l;
        }
    }

    float q0m = elu_f(rlf(a1m[Q], t)),     q0l = elu_f(rlf(a1l[Q], t));
    float q1m = elu_f(rlf(a1m[4 + Q], t)), q1l = elu_f(rlf(a1l[4 + Q], t));
    float q2m = 0.f, q2l = 0.f;
    if (EX) {
        q2m = elu_f(rlf(a1m[EX == 1 ? 3 : 7], 63));
        q2l = elu_f(rlf(a1l[EX == 1 ? 3 : 7], 63));
    }

    #pragma unroll
    for (int r = Q; r < 4; ++r) {
        Rm[r] += f4c(S.w[12], r) * q0m + f4c(S.w[14], r) * q1m;
        Rl[r] += f4c(S.w[13], r) * q0l + f4c(S.w[15], r) * q1l;
    }
    if (EX) {
        #pragma unroll
        for (int r = 0; r < 4; ++r) {
            Rm[r] += f4c(exwm, r) * q2m;
            Rl[r] += f4c(exwl, r) * q2l;
        }
    }
}

__global__ __launch_bounds__(128, 1) void made_main(
    const float* __restrict__ x,
    const float* __restrict__ mu_b0, const float* __restrict__ mu_b1,
    const float* __restrict__ mu_bo,
    const float* __restrict__ lv_b0, const float* __restrict__ lv_b1,
    const float* __restrict__ lv_bo,
    const float* __restrict__ tape,
    float* __restrict__ out)
{
    // 4-slot LDS ring, 16 KB per slot (one tape group).
    __shared__ __align__(16) float buf[4][TS];
    const int row = blockIdx.x;

    // ===== wave 1: LDS producer — tape group t -> buf[t&3], 3-step lead =====
    // Per-step: counted vmcnt(32) (group t landed, 2 more sets in flight),
    // raw s_barrier, then issue group t+3 into the slot the consumer just
    // finished (buf[(t-1)&3]).  Never drains vmcnt to 0 in the loop.
    if (threadIdx.x >= 64) {
        const int lane = threadIdx.x - 64;
        #pragma unroll
        for (int g = 0; g < 3; ++g)
            stage16(tape + (size_t)g * TS, &buf[g][0], lane);
        #pragma unroll 1
        for (int t = 0; t < 255; ++t) {
            WAITVM(32);                          // group t is in LDS
            __builtin_amdgcn_s_barrier();        // release consumer step t
            __builtin_amdgcn_sched_barrier(0);   // don't hoist next stores above
            int g = t + 3;
            if (g < 255)
                stage16(tape + (size_t)g * TS, &buf[g & 3][0], lane);
        }
        return;
    }

    // ===== wave 0: main serial loop (arithmetic identical to round 9) =====
    const int lane = threadIdx.x;

    float a0m[8], a0l[8], a1m[8], a1l[8], Rm[4], Rl[4], yv[4];
    float xv[4], bmv[4], blv[4];
    #pragma unroll
    for (int r = 0; r < 4; ++r) {
        a0m[r]     = mu_b0[lane + 64 * r];
        a0m[4 + r] = mu_b0[255 + lane + 64 * r];
        a0l[r]     = lv_b0[lane + 64 * r];
        a0l[4 + r] = lv_b0[255 + lane + 64 * r];
        a1m[r]     = mu_b1[lane + 64 * r];
        a1m[4 + r] = mu_b1[255 + lane + 64 * r];
        a1l[r]     = lv_b1[lane + 64 * r];
        a1l[4 + r] = lv_b1[255 + lane + 64 * r];
        Rm[r] = 0.f; Rl[r] = 0.f; yv[r] = 0.f;
        xv[r]  = x[row * DD + 64 * r + lane];
        bmv[r] = mu_bo[64 * r + lane];
        blv[r] = lv_bo[64 * r + lane];
    }
    if (lane == 63) {   // (63,3) slots host h=510 (A) and h=511 (B)
        a0m[3] = mu_b0[510]; a0m[7] = mu_b0[511];
        a0l[3] = lv_b0[510]; a0l[7] = lv_b0[511];
        a1m[3] = mu_b1[510]; a1m[7] = mu_b1[511];
        a1l[3] = lv_b1[510]; a1l[7] = lv_b1[511];
    }

    // appendix preloads (dead after steps 0/1)
    const float4* a4 = (const float4*)(tape + 255 * TS);
    float4 e510mA = a4[lane],       e510mB = a4[64 + lane];
    float4 e510lA = a4[128 + lane], e510lB = a4[192 + lane];
    float4 e511mA = a4[256 + lane], e511mB = a4[320 + lane];
    float4 e511lA = a4[384 + lane], e511lB = a4[448 + lane];
    float4 wo510m = a4[512 + lane], wo510l = a4[576 + lane];
    float4 wo511m = a4[640 + lane], wo511l = a4[704 + lane];

    const float4 d4 = make_float4(0.f, 0.f, 0.f, 0.f);

    float ls_sum = 0.f;

    // ---- step 0 (extra h=510), group 0 ----
    SYNC();
    {
        WSet S; rd_set(S, &buf[0][0], lane);
        stepC<0, 1>(0, lane, S, a0m, a0l, a1m, a1l, Rm, Rl, yv, xv, bmv, blv,
                    ls_sum, e510mA, e510mB, e510lA, e510lB, wo510m, wo510l);
    }

    // ---- step 1 (extra h=511), group 1 ----
    SYNC();
    {
        WSet S; rd_set(S, &buf[1][0], lane);
        stepC<0, 2>(1, lane, S, a0m, a0l, a1m, a1l, Rm, Rl, yv, xv, bmv, blv,
                    ls_sum, e511mA, e511mB, e511lA, e511lB, wo511m, wo511l);
    }

#define STEP_BODY(Q, t, tl)                                                   \
    {                                                                         \
        SYNC();                                                               \
        WSet S; rd_set(S, &buf[(t) & 3][0], lane);                            \
        stepC<Q, 0>((tl), lane, S, a0m, a0l, a1m, a1l, Rm, Rl, yv,            \
                    xv, bmv, blv, ls_sum, d4, d4, d4, d4, d4, d4);            \
    }

    #pragma unroll 1
    for (int t = 2; t < 64; ++t)    STEP_BODY(0, t, t)
    #pragma unroll 1
    for (int t = 64; t < 128; ++t)  STEP_BODY(1, t, t - 64)
    #pragma unroll 1
    for (int t = 128; t < 192; ++t) STEP_BODY(2, t, t - 128)
    #pragma unroll 1
    for (int t = 192; t < 255; ++t) STEP_BODY(3, t, t - 192)
#undef STEP_BODY

    // ---- step 255: output only ----
    {
        float mu = rlf(Rm[3], 63) + rlf(bmv[3], 63);
        float ls = 0.5f * (rlf(Rl[3], 63) + rlf(blv[3], 63));
        ls_sum += ls;
        float v = __fdividef(rlf(xv[3], 63) - mu, __expf(ls) + 1e-12f);
        yv[3] = (lane == 63) ? v : yv[3];
    }

    #pragma unroll
    for (int r = 0; r < 4; ++r) out[row * DD + 64 * r + lane] = yv[r];
    if (lane == 0) out[BB * DD + row] = ls_sum;
}

extern "C" void kernel_launch(void* const* d_in, const int* in_sizes, int n_in,
                              void* d_out, int out_size, void* d_ws, size_t ws_size,
                              hipStream_t stream) {
    const float* x     = (const float*)d_in[0];
    const float* mu_W0 = (const float*)d_in[1];
    const float* mu_b0 = (const float*)d_in[2];
    const float* mu_W1 = (const float*)d_in[3];
    const float* mu_b1 = (const float*)d_in[4];
    const float* mu_Wo = (const float*)d_in[5];
    const float* mu_bo = (const float*)d_in[6];
    const float* lv_W0 = (const float*)d_in[7];
    const float* lv_b0 = (const float*)d_in[8];
    const float* lv_W1 = (const float*)d_in[9];
    const float* lv_b1 = (const float*)d_in[10];
    const float* lv_Wo = (const float*)d_in[11];
    const float* lv_bo = (const float*)d_in[12];

    float* tape = (float*)d_ws;   // 4 MiB

    prep<<<512, 256, 0, stream>>>(mu_W0, lv_W0, mu_W1, lv_W1, mu_Wo, lv_Wo, tape);
    made_main<<<BB, 128, 0, stream>>>(x, mu_b0, mu_b1, mu_bo,
                                      lv_b0, lv_b1, lv_bo, tape, (float*)d_out);
}

// Round 2
// 183.113 us; speedup vs baseline: 1.0968x; 1.0113x over previous
//
#include <hip/hip_runtime.h>

#define DD 256
#define HH 512
#define BB 128
#define TS 4096   // floats per tape block (16 KB)

#define WAITVM(N) asm volatile("s_waitcnt vmcnt(" #N ")" ::: "memory")
#define SYNC() do { __builtin_amdgcn_s_barrier(); __builtin_amdgcn_sched_barrier(0); } while (0)

__device__ __forceinline__ float elu_f(float x) {
    return x > 0.f ? x : (__expf(x) - 1.f);
}
__device__ __forceinline__ float rlf(float v, int l) {
    return __uint_as_float(__builtin_amdgcn_readlane(__float_as_uint(v), (unsigned)l));
}
__device__ __forceinline__ float f4c(const float4& v, int r) {
    return r == 0 ? v.x : r == 1 ? v.y : r == 2 ? v.z : v.w;
}

// Unit slot map: lane L, A-reg r (0..3) <-> h = L+64r  [exception (63,3) -> h=510]
//                lane L, B-reg 4+r     <-> h = 255+L+64r [exception (63,3) -> h=511]
__device__ __forceinline__ int pmap(int h) {
    if (h == 510) return 255;
    if (h == 511) return 511;
    return (h < 255) ? (4 * (h & 63) + (h >> 6))
                     : (256 + 4 * ((h - 255) & 63) + ((h - 255) >> 6));
}
__device__ __forceinline__ int p4map(int j) {      // j in [0,256): column map
    return 4 * (j & 63) + (j >> 6);
}
__device__ __forceinline__ int w1base(int hp) {    // m at +0, l at +512
    return (hp <= 254) ? hp * TS
         : (hp <= 509) ? (hp - 255) * TS + 1024
         : 255 * TS + ((hp == 510) ? 0 : 1024);
}
__device__ __forceinline__ int wobase(int hp) {    // m at +0, l at +256
    return (hp <= 254) ? hp * TS + 3072
         : (hp <= 509) ? (hp - 255) * TS + 3584
         : 255 * TS + ((hp == 510) ? 2048 : 2560);
}

// Tape block i (4096 floats), rows lane-packed [pos = p(h) or p4(j)]:
//  [0/512]    W1T[i]     m/l     [1024/1536] W1T[i+255] m/l
//  [2048/2560] W0T[i]    m/l     [3072/3328] WoT[i]     m/l (256)
//  [3584/3840] WoT[i+255] m/l
// Block 255 = appendix: W1T[510] m/l @0/512, W1T[511] m/l @1024/1536,
//  WoT[510] m/l @2048/2304, WoT[511] m/l @2560/2816.  [3072..4095 unused]
__global__ __launch_bounds__(256) void prep(
    const float* __restrict__ w0m_, const float* __restrict__ w0l_,
    const float* __restrict__ w1m_, const float* __restrict__ w1l_,
    const float* __restrict__ wom_, const float* __restrict__ wol_,
    float* __restrict__ tape)
{
    __shared__ float tm[32][33], tl[32][33];
    const int tx = threadIdx.x & 31, ty = threadIdx.x >> 5;
    const unsigned b = blockIdx.x;

    if (b < 256) {                              // W1: 16 h-tiles x 16 hp-tiles
        const int h0 = (int)(b >> 4) << 5, hp0 = (int)(b & 15) << 5;
        #pragma unroll
        for (int j = 0; j < 4; ++j) {
            int r = ty + 8 * j;
            tm[r][tx] = w1m_[(h0 + r) * HH + hp0 + tx];
            tl[r][tx] = w1l_[(h0 + r) * HH + hp0 + tx];
        }
        __syncthreads();
        #pragma unroll
        for (int j = 0; j < 4; ++j) {
            int hp = hp0 + ty + 8 * j;
            int h  = h0 + tx;
            int dh_h = (h <= 254) ? h + 1 : (h <= 509 ? h - 254 : h - 509);
            int dh_p = (hp <= 254) ? hp + 1 : (hp <= 509 ? hp - 254 : hp - 509);
            float mask = (dh_h >= dh_p) ? 1.f : 0.f;
            int base = w1base(hp), p = pmap(h);
            tape[base + p]       = mask * tm[tx][ty + 8 * j];
            tape[base + 512 + p] = mask * tl[tx][ty + 8 * j];
        }
    } else if (b < 384) {                       // W0: 16 h-tiles x 8 i-tiles
        const int b2 = (int)b - 256;
        const int h0 = (b2 >> 3) << 5, i0 = (b2 & 7) << 5;
        #pragma unroll
        for (int j = 0; j < 4; ++j) {
            int r = ty + 8 * j;
            tm[r][tx] = w0m_[(h0 + r) * DD + i0 + tx];
            tl[r][tx] = w0l_[(h0 + r) * DD + i0 + tx];
        }
        __syncthreads();
        #pragma unroll
        for (int j = 0; j < 4; ++j) {
            int i = i0 + ty + 8 * j;
            int h = h0 + tx;
            int p = pmap(h);
            tape[i * TS + 2048 + p] = tm[tx][ty + 8 * j];
            tape[i * TS + 2560 + p] = tl[tx][ty + 8 * j];
        }
    } else {                                    // Wo: 8 j-tiles x 16 hp-tiles
        const int b3 = (int)b - 384;
        const int j0 = (b3 >> 4) << 5, hp0 = (b3 & 15) << 5;
        #pragma unroll
        for (int j = 0; j < 4; ++j) {
            int r = ty + 8 * j;
            tm[r][tx] = wom_[(j0 + r) * HH + hp0 + tx];
            tl[r][tx] = wol_[(j0 + r) * HH + hp0 + tx];
        }
        __syncthreads();
        #pragma unroll
        for (int j = 0; j < 4; ++j) {
            int hp = hp0 + ty + 8 * j;
            int jj = j0 + tx;
            int base = wobase(hp), p = p4map(jj);
            tape[base + p]       = tm[tx][ty + 8 * j];
            tape[base + 256 + p] = tl[tx][ty + 8 * j];
        }
    }
}

// ================================ main =====================================
struct WSet { float4 w[16]; };

// producer: stage one 16 KB group into an LDS ring slot via direct-to-LDS DMA.
// Layout is linear: chunk k, lane L -> lds[k*256 + 4L .. +3] (wave-uniform base
// + lane*16, exactly the HW pattern of global_load_lds width 16).
__device__ __forceinline__ void stage16(const float* g, float* l, int lane) {
    #pragma unroll
    for (int k = 0; k < 16; ++k) {
        __builtin_amdgcn_global_load_lds(
            (const __attribute__((address_space(1))) void*)(g + 256 * k + 4 * lane),
            (__attribute__((address_space(3))) void*)(l + 256 * k),
            16, 0, 0);
    }
}

// consumer: LDS ring slot -> register weight set (16x ds_read_b128,
// stride-16B contiguous per lane -> conflict-free).
__device__ __forceinline__ void rd_set(WSet& S, const float* b, int lane) {
    const float4* p = (const float4*)b;
    #pragma unroll
    for (int k = 0; k < 16; ++k) S.w[k] = p[64 * k + lane];
}

// w[0..3]=W1T[i] mA,mB,lA,lB  w[4..7]=W1T[i+255] mA,mB,lA,lB
// w[8..11]=W0T[i] mA,mB,lA,lB  w[12..15]=WoT[i]m, WoT[i]l, WoT[i+255]m, WoT[i+255]l
template<int Q, int EX>
__device__ __forceinline__ void stepC(
    int t, int lane, const WSet& S,
    float (&a0m)[8], float (&a0l)[8], float (&a1m)[8], float (&a1l)[8],
    float (&Rm)[4], float (&Rl)[4], float (&yv)[4],
    const float (&xv)[4], const float (&bmv)[4], const float (&blv)[4],
    float& ls_sum,
    const float4& exmA, const float4& exmB, const float4& exlA, const float4& exlB,
    const float4& exwm, const float4& exwl)
{
    float mu = rlf(Rm[Q], t) + rlf(bmv[Q], t);
    float ls = 0.5f * (rlf(Rl[Q], t) + rlf(blv[Q], t));
    ls_sum += ls;
    float v = __fdividef(rlf(xv[Q], t) - mu, __expf(ls) + 1e-12f);
    yv[Q] = (lane == t) ? v : yv[Q];

    #pragma unroll
    for (int r = Q; r < 4; ++r) {
        a0m[r]     += v * f4c(S.w[8], r);
        a0m[4 + r] += v * f4c(S.w[9], r);
        a0l[r]     += v * f4c(S.w[10], r);
        a0l[4 + r] += v * f4c(S.w[11], r);
    }

    float p0m = elu_f(rlf(a0m[Q], t)),     p0l = elu_f(rlf(a0l[Q], t));
    float p1m = elu_f(rlf(a0m[4 + Q], t)), p1l = elu_f(rlf(a0l[4 + Q], t));
    float p2m = 0.f, p2l = 0.f;
    if (EX) {
        p2m = elu_f(rlf(a0m[EX == 1 ? 3 : 7], 63));
        p2l = elu_f(rlf(a0l[EX == 1 ? 3 : 7], 63));
    }

    #pragma unroll
    for (int r = Q; r < 4; ++r) {
        a1m[r]     += f4c(S.w[0], r) * p0m + f4c(S.w[4], r) * p1m;
        a1m[4 + r] += f4c(S.w[1], r) * p0m + f4c(S.w[5], r) * p1m;
        a1l[r]     += f4c(S.w[2], r) * p0l + f4c(S.w[6], r) * p1l;
        a1l[4 + r] += f4c(S.w[3], r) * p0l + f4c(S.w[7], r) * p1l;
    }
    if (EX) {
        #pragma unroll
        for (int r = 0; r < 4; ++r) {
            a1m[r]     += f4c(exmA, r) * p2m;
            a1m[4 + r] += f4c(exmB, r) * p2m;
            a1l[r]     += f4c(exlA, r) * p2l;
            a1l[4 + r] += f4c(exlB, r) * p2l;
        }
    }

    float q0m = elu_f(rlf(a1m[Q], t)),     q0l = elu_f(rlf(a1l[Q], t));
    float q1m = elu_f(rlf(a1m[4 + Q], t)), q1l = elu_f(rlf(a1l[4 + Q], t));
    float q2m = 0.f, q2l = 0.f;
    if (EX) {
        q2m = elu_f(rlf(a1m[EX == 1 ? 3 : 7], 63));
        q2l = elu_f(rlf(a1l[EX == 1 ? 3 : 7], 63));
    }

    #pragma unroll
    for (int r = Q; r < 4; ++r) {
        Rm[r] += f4c(S.w[12], r) * q0m + f4c(S.w[14], r) * q1m;
        Rl[r] += f4c(S.w[13], r) * q0l + f4c(S.w[15], r) * q1l;
    }
    if (EX) {
        #pragma unroll
        for (int r = 0; r < 4; ++r) {
            Rm[r] += f4c(exwm, r) * q2m;
            Rl[r] += f4c(exwl, r) * q2l;
        }
    }
}

__global__ __launch_bounds__(128, 1) void made_main(
    const float* __restrict__ x,
    const float* __restrict__ mu_b0, const float* __restrict__ mu_b1,
    const float* __restrict__ mu_bo,
    const float* __restrict__ lv_b0, const float* __restrict__ lv_b1,
    const float* __restrict__ lv_bo,
    const float* __restrict__ tape,
    float* __restrict__ out)
{
    // 4-slot LDS ring, 16 KB per slot (one tape group).
    __shared__ __align__(16) float buf[4][TS];
    const int row = blockIdx.x;

    // ===== wave 1: LDS producer — tape group t -> buf[t&3], 3-step lead =====
    // Invariant: at barrier t, groups <= t+1 are LDS-resident (consumer
    // prefetches S_{t+1} into registers during step t).  Counted vmcnt(16)
    // lands exactly one group per step; tail (t>=253) drains to 0.
    if (threadIdx.x >= 64) {
        const int lane = threadIdx.x - 64;
        #pragma unroll
        for (int g = 0; g < 3; ++g)
            stage16(tape + (size_t)g * TS, &buf[g][0], lane);
        #pragma unroll 1
        for (int t = 0; t < 255; ++t) {
            if (t < 253) { WAITVM(16); } else { WAITVM(0); }
            __builtin_amdgcn_s_barrier();        // release consumer step t
            __builtin_amdgcn_sched_barrier(0);   // don't hoist next stores above
            int g = t + 3;
            if (g < 255)
                stage16(tape + (size_t)g * TS, &buf[g & 3][0], lane);
        }
        return;
    }

    // ===== wave 0: main serial loop (arithmetic identical to round 9) =====
    const int lane = threadIdx.x;

    float a0m[8], a0l[8], a1m[8], a1l[8], Rm[4], Rl[4], yv[4];
    float xv[4], bmv[4], blv[4];
    #pragma unroll
    for (int r = 0; r < 4; ++r) {
        a0m[r]     = mu_b0[lane + 64 * r];
        a0m[4 + r] = mu_b0[255 + lane + 64 * r];
        a0l[r]     = lv_b0[lane + 64 * r];
        a0l[4 + r] = lv_b0[255 + lane + 64 * r];
        a1m[r]     = mu_b1[lane + 64 * r];
        a1m[4 + r] = mu_b1[255 + lane + 64 * r];
        a1l[r]     = lv_b1[lane + 64 * r];
        a1l[4 + r] = lv_b1[255 + lane + 64 * r];
        Rm[r] = 0.f; Rl[r] = 0.f; yv[r] = 0.f;
        xv[r]  = x[row * DD + 64 * r + lane];
        bmv[r] = mu_bo[64 * r + lane];
        blv[r] = lv_bo[64 * r + lane];
    }
    if (lane == 63) {   // (63,3) slots host h=510 (A) and h=511 (B)
        a0m[3] = mu_b0[510]; a0m[7] = mu_b0[511];
        a0l[3] = lv_b0[510]; a0l[7] = lv_b0[511];
        a1m[3] = mu_b1[510]; a1m[7] = mu_b1[511];
        a1l[3] = lv_b1[510]; a1l[7] = lv_b1[511];
    }

    // appendix preloads (dead after steps 0/1)
    const float4* a4 = (const float4*)(tape + 255 * TS);
    float4 e510mA = a4[lane],       e510mB = a4[64 + lane];
    float4 e510lA = a4[128 + lane], e510lB = a4[192 + lane];
    float4 e511mA = a4[256 + lane], e511mB = a4[320 + lane];
    float4 e511lA = a4[384 + lane], e511lB = a4[448 + lane];
    float4 wo510m = a4[512 + lane], wo510l = a4[576 + lane];
    float4 wo511m = a4[640 + lane], wo511l = a4[704 + lane];

    const float4 d4 = make_float4(0.f, 0.f, 0.f, 0.f);

    float ls_sum = 0.f;
    WSet A, B;

    // ---- step 0 (extra h=510), group 0; prefetch S_0 AND S_1 (both resident
    //      at barrier 0 under the t+1 invariant) ----
    SYNC();
    rd_set(A, &buf[0][0], lane);
    rd_set(B, &buf[1][0], lane);
    stepC<0, 1>(0, lane, A, a0m, a0l, a1m, a1l, Rm, Rl, yv, xv, bmv, blv,
                ls_sum, e510mA, e510mB, e510lA, e510lB, wo510m, wo510l);

    // ---- step 1 (extra h=511), group 1; prefetch S_2 ----
    SYNC();
    rd_set(A, &buf[2][0], lane);
    stepC<0, 2>(1, lane, B, a0m, a0l, a1m, a1l, Rm, Rl, yv, xv, bmv, blv,
                ls_sum, e511mA, e511mB, e511lA, e511lB, wo511m, wo511l);

    // ---- steady state: compute S_t from registers, prefetch S_{t+1} ----
#define PAIR_BODY(Q, t, tl)                                                   \
    {                                                                         \
        SYNC();                                                               \
        rd_set(B, &buf[((t) + 1) & 3][0], lane);                              \
        stepC<Q, 0>((tl), lane, A, a0m, a0l, a1m, a1l, Rm, Rl, yv,            \
                    xv, bmv, blv, ls_sum, d4, d4, d4, d4, d4, d4);            \
        SYNC();                                                               \
        rd_set(A, &buf[((t) + 2) & 3][0], lane);                              \
        stepC<Q, 0>((tl) + 1, lane, B, a0m, a0l, a1m, a1l, Rm, Rl, yv,        \
                    xv, bmv, blv, ls_sum, d4, d4, d4, d4, d4, d4);            \
    }

    #pragma unroll 1
    for (int t = 2; t < 64; t += 2)    PAIR_BODY(0, t, t)
    #pragma unroll 1
    for (int t = 64; t < 128; t += 2)  PAIR_BODY(1, t, t - 64)
    #pragma unroll 1
    for (int t = 128; t < 192; t += 2) PAIR_BODY(2, t, t - 128)
    #pragma unroll 1
    for (int t = 192; t < 254; t += 2) PAIR_BODY(3, t, t - 192)
#undef PAIR_BODY

    // ---- step 254 (A = group 254, prefetched during step 253) ----
    SYNC();
    stepC<3, 0>(62, lane, A, a0m, a0l, a1m, a1l, Rm, Rl, yv, xv, bmv, blv,
                ls_sum, d4, d4, d4, d4, d4, d4);

    // ---- step 255: output only ----
    {
        float mu = rlf(Rm[3], 63) + rlf(bmv[3], 63);
        float ls = 0.5f * (rlf(Rl[3], 63) + rlf(blv[3], 63));
        ls_sum += ls;
        float v = __fdividef(rlf(xv[3], 63) - mu, __expf(ls) + 1e-12f);
        yv[3] = (lane == 63) ? v : yv[3];
    }

    #pragma unroll
    for (int r = 0; r < 4; ++r) out[row * DD + 64 * r + lane] = yv[r];
    if (lane == 0) out[BB * DD + row] = ls_sum;
}

extern "C" void kernel_launch(void* const* d_in, const int* in_sizes, int n_in,
                              void* d_out, int out_size, void* d_ws, size_t ws_size,
                              hipStream_t stream) {
    const float* x     = (const float*)d_in[0];
    const float* mu_W0 = (const float*)d_in[1];
    const float* mu_b0 = (const float*)d_in[2];
    const float* mu_W1 = (const float*)d_in[3];
    const float* mu_b1 = (const float*)d_in[4];
    const float* mu_Wo = (const float*)d_in[5];
    const float* mu_bo = (const float*)d_in[6];
    const float* lv_W0 = (const float*)d_in[7];
    const float* lv_b0 = (const float*)d_in[8];
    const float* lv_W1 = (const float*)d_in[9];
    const float* lv_b1 = (const float*)d_in[10];
    const float* lv_Wo = (const float*)d_in[11];
    const float* lv_bo = (const float*)d_in[12];

    float* tape = (float*)d_ws;   // 4 MiB

    prep<<<512, 256, 0, stream>>>(mu_W0, lv_W0, mu_W1, lv_W1, mu_Wo, lv_Wo, tape);
    made_main<<<BB, 128, 0, stream>>>(x, mu_b0, mu_b1, mu_bo,
                                      lv_b0, lv_b1, lv_bo, tape, (float*)d_out);
}